// Round 8
// baseline (1977.070 us; speedup 1.0000x reference)
//
#include <hip/hip_runtime.h>

// ---------------------------------------------------------------------------
// TrueMambaBlock on MI355X — fp32 pipeline v3: conv+xproj+dt+scan+gate+OUTPROJ
// fused per (seq, dir) block. vs v2: gated-buffer round trip and k_outproj
// deleted (−320 MB traffic); k_fused emits per-direction outproj partials
// accD[orient][dir][tok][64]; k_final sums 4 streams * 0.25. ws = 144 MiB.
// B=1, C=64, H=W=256, D_INNER=128, D_STATE=16, D_CONV=4, DT_RANK=4
// ---------------------------------------------------------------------------

// ---- ws layout (float offsets) ---------------------------------------------
static constexpr size_t OFF_YN   = 0;                    // 65536*64 normalized tokens [tok][c]
static constexpr size_t OFF_XZ   = OFF_YN + 4194304;     // 65536*256 xz (per orientation, reused)
static constexpr size_t OFF_ACCD = OFF_XZ + 16777216;    // 4 * 65536*64 outproj partials (+red alias)
static constexpr size_t WS_FLOATS = OFF_ACCD + 16777216; // 37,748,736 floats = 144 MiB

__device__ __forceinline__ float silu_f(float v) { return v / (1.f + __expf(-v)); }

// ---- zero the reduction accumulator ---------------------------------------
__global__ void k_zero(float* r) {
    if (threadIdx.x < 2) r[threadIdx.x] = 0.f;
}

// ---- global mean / meansq reduction over 4,194,304 floats ------------------
__global__ __launch_bounds__(256) void k_reduce(const float* __restrict__ x, float* __restrict__ red) {
    int tid = blockIdx.x * 256 + threadIdx.x;           // 262144 threads
    const float4* x4 = (const float4*)x;
    float s = 0.f, sq = 0.f;
    #pragma unroll
    for (int i = 0; i < 4; i++) {
        float4 v = x4[tid + i * 262144];
        s  += v.x + v.y + v.z + v.w;
        sq += v.x * v.x + v.y * v.y + v.z * v.z + v.w * v.w;
    }
    #pragma unroll
    for (int off = 32; off; off >>= 1) {
        s  += __shfl_down(s, off);
        sq += __shfl_down(sq, off);
    }
    __shared__ float ls[8], lq[8];
    int wid = threadIdx.x >> 6, lane = threadIdx.x & 63;
    if (lane == 0) { ls[wid] = s; lq[wid] = sq; }
    __syncthreads();
    if (threadIdx.x == 0) {
        float ts = 0.f, tq = 0.f;
        for (int w = 0; w < 4; w++) { ts += ls[w]; tq += lq[w]; }
        atomicAdd(&red[0], ts);
        atomicAdd(&red[1], tq);
    }
}

// ---- normalize + transpose [c][hw] -> [tok][c] -----------------------------
__global__ __launch_bounds__(256) void k_norm(const float* __restrict__ x, const float* __restrict__ red,
                                              const float* __restrict__ gw, const float* __restrict__ gb,
                                              float* __restrict__ yn) {
    __shared__ float tile[64][65];
    int hw0 = blockIdx.x * 64;
    float mean = red[0] * (1.f / 4194304.f);
    float var  = red[1] * (1.f / 4194304.f) - mean * mean;
    float rstd = rsqrtf(var + 1e-5f);
    int tx = threadIdx.x & 63, ty = threadIdx.x >> 6;
    #pragma unroll
    for (int i = 0; i < 16; i++) {
        int c = i * 4 + ty;
        tile[c][tx] = x[c * 65536 + hw0 + tx];
    }
    __syncthreads();
    int c = tx;
    float sc = gw[c] * rstd;
    float bb = gb[c] - mean * sc;
    #pragma unroll
    for (int i = 0; i < 16; i++) {
        int m = i * 4 + ty;
        yn[(size_t)(hw0 + m) * 64 + c] = tile[c][m] * sc + bb;
    }
}

// ---- xz GEMM: xz[tok][256] = yn_token @ in_w.T ------------------------------
// grid 2048: bid>>1 = 64-token tile, bid&1 = 128-wide N chunk.
// orient 0: token t -> yn row t; orient 1 (col): t=(s,p) -> yn row p*256+s
__global__ __launch_bounds__(256) void k_xz(const float* __restrict__ yn, const float* __restrict__ in_w,
                                            float* __restrict__ xz, int orient) {
    __shared__ __align__(16) float tk[64][68];    // [k][m]
    __shared__ __align__(16) float wl[64][132];   // [k][n]
    int mt = blockIdx.x >> 1, nc = blockIdx.x & 1;
    int t0 = mt * 64;
    int tid = threadIdx.x;
    {   // stage tokens, transposed to k-major
        int k = tid & 63, mg = tid >> 6;
        for (int ms = 0; ms < 64; ms += 4) {
            int m = ms + mg;
            int t = t0 + m;
            size_t addr;
            if (orient == 0) addr = (size_t)t * 64 + k;
            else { int s = t >> 8, p = t & 255; addr = (size_t)(p * 256 + s) * 64 + k; }
            tk[k][m] = yn[addr];
        }
    }
    {   // stage weights chunk (128 n), transposed to k-major
        int k = tid & 63, ng = tid >> 6;
        for (int i = 0; i < 32; i++) {
            int n = i * 4 + ng;
            wl[k][n] = in_w[(size_t)(nc * 128 + n) * 64 + k];
        }
    }
    __syncthreads();
    int m0 = (tid & 15) * 4, n0 = (tid >> 4) * 8;
    float acc[4][8];
    #pragma unroll
    for (int i = 0; i < 4; i++)
        #pragma unroll
        for (int j = 0; j < 8; j++) acc[i][j] = 0.f;
    #pragma unroll 4
    for (int k = 0; k < 64; k++) {
        float4 tv = *(const float4*)&tk[k][m0];
        float tvf[4] = { tv.x, tv.y, tv.z, tv.w };
        #pragma unroll
        for (int i4 = 0; i4 < 2; i4++) {
            float4 wv = *(const float4*)&wl[k][n0 + i4 * 4];
            float wvf[4] = { wv.x, wv.y, wv.z, wv.w };
            #pragma unroll
            for (int m = 0; m < 4; m++)
                #pragma unroll
                for (int j = 0; j < 4; j++)
                    acc[m][i4 * 4 + j] += tvf[m] * wvf[j];
        }
    }
    #pragma unroll
    for (int m = 0; m < 4; m++) {
        size_t t = t0 + m0 + m;
        #pragma unroll
        for (int i4 = 0; i4 < 2; i4++) {
            float4 v = { acc[m][i4 * 4 + 0], acc[m][i4 * 4 + 1], acc[m][i4 * 4 + 2], acc[m][i4 * 4 + 3] };
            *(float4*)&xz[t * 256 + nc * 128 + n0 + i4 * 4] = v;
        }
    }
}

// ---- fused conv4+silu + xproj + dt + scan + gating + outproj ----------------
// grid (256, 2): bid.x = seq s, bid.y = dir. 512 threads.
// Per 64-token chunk (fwd: c=0..3, bwd: c=3..0):
//   stage xz x-window [70][128] -> conv+silu (16 regs/thread) -> xcl [64][132]
//   -> xproj x_dbl [64][40] -> 64-step scan (dt recomputed, 1-step operand
//   prefetch; q==0 writes ycore=y+D*x over consumed xcl slot) -> gating
//   IN-PLACE in LDS (y*silu(z), z from global) -> outproj GEMM
//   (64tok x 64out x k128, out_w via L1) -> accD partial write.
// LDS hazards: scan slot write confined to the reader wave; all other phase
// transitions barrier-separated.
__global__ __launch_bounds__(512) void k_fused(const float* __restrict__ xz,
                                               const float* __restrict__ conv_w, const float* __restrict__ conv_b,
                                               const float* __restrict__ xproj_w,
                                               const float* __restrict__ dt_w, const float* __restrict__ dt_b,
                                               const float* __restrict__ A_log, const float* __restrict__ Dw,
                                               const float* __restrict__ out_w,
                                               float* __restrict__ accD) {
    __shared__ __align__(16) float sm[16272];
    float* xw = sm;                       // window [70][128]; reused as xcl/ycore/gated [64][132]
    float* wp = sm + 8960;                // xproj [36][132]
    float* xd = sm + 8960 + 4752;         // x_dbl [64][40]
    const int tid = threadIdx.x;
    const int s = blockIdx.x, dir = blockIdx.y;
    const int seqbase = s * 256;

    // stage xproj weights once (36*128 = 4608 elems)
    for (int i = 0; i < 10; i++) {
        int lin = i * 512 + tid;
        if (lin < 4608) {
            int n = lin >> 7, k = lin & 127;
            wp[n * 132 + k] = xproj_w[lin];
        }
    }

    // per-thread constants
    const int d  = tid >> 2, q = tid & 3, q4 = q * 4;   // scan mapping
    const int dg = tid & 127;                            // conv/gating channel
    const int mg = tid >> 7;                             // 0..3
    const float4 cw  = ((const float4*)conv_w)[dg];
    const float  cb  = conv_b[dg];
    const float4 dwv = ((const float4*)dt_w)[d];
    const float  dbv = dt_b[d];
    const float A0 = -__expf(A_log[d * 16 + q4 + 0]);
    const float A1 = -__expf(A_log[d * 16 + q4 + 1]);
    const float A2 = -__expf(A_log[d * 16 + q4 + 2]);
    const float A3 = -__expf(A_log[d * 16 + q4 + 3]);
    const float Dv = Dw[d];
    float* ap = accD + (size_t)dir * 4194304 + (size_t)seqbase * 64;

    float h0 = 0.f, h1 = 0.f, h2 = 0.f, h3 = 0.f;

    for (int ci = 0; ci < 4; ci++) {
        const int c  = dir ? 3 - ci : ci;
        const int p0 = c * 64;
        __syncthreads();   // prev GEMM reads / wp-stage complete before window restage
        // stage x window positions p0-3 .. p0+66 (zero padded), 70*128 elems
        for (int i = 0; i < 18; i++) {
            int lin = i * 512 + tid;
            if (lin < 8960) {
                int pi = lin >> 7, dd = lin & 127;
                int pp = p0 - 3 + pi;
                float v = 0.f;
                if (pp >= 0 && pp < 256) v = xz[(size_t)(seqbase + pp) * 256 + dd];
                xw[lin] = v;
            }
        }
        __syncthreads();
        // conv + silu -> regs (16 outputs/thread: m = i*4+mg, channel dg)
        float cv[16];
        #pragma unroll
        for (int i = 0; i < 16; i++) {
            int m = i * 4 + mg;
            float v;
            if (dir == 0)
                v = cw.x * xw[m * 128 + dg] + cw.y * xw[(m + 1) * 128 + dg] +
                    cw.z * xw[(m + 2) * 128 + dg] + cw.w * xw[(m + 3) * 128 + dg];
            else
                v = cw.x * xw[(m + 6) * 128 + dg] + cw.y * xw[(m + 5) * 128 + dg] +
                    cw.z * xw[(m + 4) * 128 + dg] + cw.w * xw[(m + 3) * 128 + dg];
            v += cb;
            cv[i] = silu_f(v);
        }
        __syncthreads();   // all conv reads of window done
        #pragma unroll
        for (int i = 0; i < 16; i++) {
            int m = i * 4 + mg;
            xw[m * 132 + dg] = cv[i];   // xcl [64][132]
        }
        __syncthreads();
        // xproj: m = tid>>3 (0..63), g = tid&7, outputs n = g+8j (n<36)
        {
            const int m = tid >> 3, g = tid & 7;
            float acc5[5] = { 0.f, 0.f, 0.f, 0.f, 0.f };
            for (int k4 = 0; k4 < 32; k4++) {
                float4 xv = *(const float4*)&xw[m * 132 + k4 * 4];
                #pragma unroll
                for (int j = 0; j < 5; j++) {
                    int n = g + 8 * j;
                    if (n < 36) {
                        float4 wv = *(const float4*)&wp[n * 132 + k4 * 4];
                        acc5[j] += xv.x * wv.x + xv.y * wv.y + xv.z * wv.z + xv.w * wv.w;
                    }
                }
            }
            #pragma unroll
            for (int j = 0; j < 5; j++) {
                int n = g + 8 * j;
                if (n < 36) xd[m * 40 + n] = acc5[j];
            }
        }
        __syncthreads();
        // scan: 64 steps (bwd reversed), operands prefetched 1 step ahead
        {
            int t = dir ? 63 : 0;
            const int tstep = dir ? -1 : 1;
            float4 r = *(const float4*)&xd[t * 40];
            float dt_n = dbv + r.x * dwv.x + r.y * dwv.y + r.z * dwv.z + r.w * dwv.w;
            dt_n = (dt_n > 20.f) ? dt_n : log1pf(__expf(dt_n));
            float  xv_n = xw[t * 132 + d];
            float4 B4_n = *(const float4*)&xd[t * 40 + 4 + q4];
            float4 C4_n = *(const float4*)&xd[t * 40 + 20 + q4];
            float e0_n = __expf(dt_n * A0), e1_n = __expf(dt_n * A1);
            float e2_n = __expf(dt_n * A2), e3_n = __expf(dt_n * A3);
            for (int step = 0; step < 64; step++) {
                const int tw = t;
                const float dtv = dt_n, xv = xv_n;
                const float4 B4 = B4_n, C4 = C4_n;
                const float e0 = e0_n, e1 = e1_n, e2 = e2_n, e3 = e3_n;
                if (step < 63) {
                    t += tstep;
                    float4 rn = *(const float4*)&xd[t * 40];
                    dt_n = dbv + rn.x * dwv.x + rn.y * dwv.y + rn.z * dwv.z + rn.w * dwv.w;
                    dt_n = (dt_n > 20.f) ? dt_n : log1pf(__expf(dt_n));
                    xv_n = xw[t * 132 + d];
                    B4_n = *(const float4*)&xd[t * 40 + 4 + q4];
                    C4_n = *(const float4*)&xd[t * 40 + 20 + q4];
                    e0_n = __expf(dt_n * A0); e1_n = __expf(dt_n * A1);
                    e2_n = __expf(dt_n * A2); e3_n = __expf(dt_n * A3);
                }
                const float dx = dtv * xv;
                h0 = e0 * h0 + dx * B4.x;
                h1 = e1 * h1 + dx * B4.y;
                h2 = e2 * h2 + dx * B4.z;
                h3 = e3 * h3 + dx * B4.w;
                float y = h0 * C4.x + h1 * C4.y + h2 * C4.z + h3 * C4.w;
                y += __shfl_xor(y, 1);
                y += __shfl_xor(y, 2);
                if (q == 0) xw[tw * 132 + d] = y + xv * Dv;   // ycore over consumed slot
            }
        }
        __syncthreads();
        // gating IN-PLACE: xw[m][dg] = ycore * silu(z), z from global (coalesced)
        #pragma unroll
        for (int i = 0; i < 16; i++) {
            int m = i * 4 + mg;
            float yc = xw[m * 132 + dg];
            float zv = xz[(size_t)(seqbase + p0 + m) * 256 + 128 + dg];
            xw[m * 132 + dg] = yc * silu_f(zv);
        }
        __syncthreads();
        // outproj GEMM: y[m][n] = sum_d gated[m][d] * out_w[n][d]
        // thread: m = tid>>3, n = (tid&7)*8 .. +7. LDS row broadcast per
        // 8-lane group; rows hit disjoint bank quads (132 % 32 == 4).
        {
            const int m = tid >> 3, n0 = (tid & 7) * 8;
            float a8[8] = { 0.f, 0.f, 0.f, 0.f, 0.f, 0.f, 0.f, 0.f };
            for (int k4 = 0; k4 < 32; k4++) {
                float4 xv = *(const float4*)&xw[m * 132 + k4 * 4];
                #pragma unroll
                for (int nn = 0; nn < 8; nn++) {
                    float4 wv = *(const float4*)&out_w[(n0 + nn) * 128 + k4 * 4];
                    a8[nn] += xv.x * wv.x + xv.y * wv.y + xv.z * wv.z + xv.w * wv.w;
                }
            }
            float4 v0 = { a8[0], a8[1], a8[2], a8[3] };
            float4 v1 = { a8[4], a8[5], a8[6], a8[7] };
            *(float4*)&ap[(size_t)(p0 + m) * 64 + n0]     = v0;
            *(float4*)&ap[(size_t)(p0 + m) * 64 + n0 + 4] = v1;
        }
    }
}

// ---- final: out = x + proj_w @ (0.25 * (Rf + Rb + Cf^T + Cb^T)) -------------
__global__ __launch_bounds__(256) void k_final(const float* __restrict__ accD,
                                               const float* __restrict__ pw, const float* __restrict__ x,
                                               float* __restrict__ out) {
    __shared__ __align__(16) float tk[64][68];
    __shared__ __align__(16) float wl[64][68];
    int t0 = blockIdx.x * 64, tid = threadIdx.x;
    int hh = t0 >> 8, w0 = t0 & 255;
    for (int i = 0; i < 16; i++) {
        int m = i * 4 + (tid >> 6), k = tid & 63;
        size_t rt = (size_t)(t0 + m) * 64 + k;
        size_t ct = (size_t)((w0 + m) * 256 + hh) * 64 + k;
        tk[k][m] = 0.25f * (accD[rt] + accD[4194304 + rt] +
                            accD[8388608 + ct] + accD[12582912 + ct]);
    }
    for (int i = 0; i < 16; i++) {
        int n = i * 4 + (tid >> 6), k = tid & 63;
        wl[k][n] = pw[n * 64 + k];
    }
    __syncthreads();
    int m0 = (tid & 15) * 4, n0 = (tid >> 4) * 4;
    float a4[4][4];
    #pragma unroll
    for (int i = 0; i < 4; i++)
        #pragma unroll
        for (int j = 0; j < 4; j++) a4[i][j] = 0.f;
    #pragma unroll 4
    for (int k = 0; k < 64; k++) {
        float4 tv = *(const float4*)&tk[k][m0];
        float4 wv = *(const float4*)&wl[k][n0];
        float tvf[4] = { tv.x, tv.y, tv.z, tv.w };
        float wvf[4] = { wv.x, wv.y, wv.z, wv.w };
        #pragma unroll
        for (int m = 0; m < 4; m++)
            #pragma unroll
            for (int j = 0; j < 4; j++)
                a4[m][j] += tvf[m] * wvf[j];
    }
    #pragma unroll
    for (int j = 0; j < 4; j++) {
        int n = n0 + j;
        float4 r = *(const float4*)&x[(size_t)n * 65536 + t0 + m0];
        float4 v = { a4[0][j] + r.x, a4[1][j] + r.y, a4[2][j] + r.z, a4[3][j] + r.w };
        *(float4*)&out[(size_t)n * 65536 + t0 + m0] = v;
    }
}

// ---------------------------------------------------------------------------
extern "C" void kernel_launch(void* const* d_in, const int* in_sizes, int n_in,
                              void* d_out, int out_size, void* d_ws, size_t ws_size,
                              hipStream_t stream) {
    (void)n_in; (void)out_size;
    if (ws_size < WS_FLOATS * sizeof(float)) return;  // refuse rather than corrupt

    float* ws = (float*)d_ws;
    const float* x    = (const float*)d_in[0];
    const float* gn_w = (const float*)d_in[1];
    const float* gn_b = (const float*)d_in[2];

    // Input ordering: setup_inputs() dict order puts proj_w at index 3,
    // row params at 4..12, col at 13..21. Detect reference-arg order as fallback.
    int rbase, cbase;
    const float* proj_w;
    if (in_sizes[3] == 64 * 64) { proj_w = (const float*)d_in[3]; rbase = 4; cbase = 13; }
    else                        { rbase = 3; cbase = 12; proj_w = (const float*)d_in[21]; }

    float* yn   = ws + OFF_YN;
    float* xzb  = ws + OFF_XZ;
    float* accD = ws + OFF_ACCD;  // [4][65536][64]: Rf, Rb, Cf, Cb
    float* red  = ws + OFF_ACCD;  // alias: red live k_zero..k_norm only

    k_zero<<<1, 64, 0, stream>>>(red);
    k_reduce<<<1024, 256, 0, stream>>>(x, red);
    k_norm<<<1024, 256, 0, stream>>>(x, red, gn_w, gn_b, yn);

    for (int o = 0; o < 2; o++) {
        int base = (o == 0) ? rbase : cbase;
        const float* in_w    = (const float*)d_in[base + 0];
        const float* conv_w  = (const float*)d_in[base + 1];
        const float* conv_b  = (const float*)d_in[base + 2];
        const float* xproj_w = (const float*)d_in[base + 3];
        const float* dt_w    = (const float*)d_in[base + 4];
        const float* dt_b    = (const float*)d_in[base + 5];
        const float* A_log   = (const float*)d_in[base + 6];
        const float* Dp      = (const float*)d_in[base + 7];
        const float* out_w   = (const float*)d_in[base + 8];

        k_xz<<<2048, 256, 0, stream>>>(yn, in_w, xzb, o);
        k_fused<<<dim3(256, 2), 512, 0, stream>>>(xzb, conv_w, conv_b, xproj_w,
                                                  dt_w, dt_b, A_log, Dp, out_w,
                                                  accD + (size_t)o * 8388608);
    }

    k_final<<<1024, 256, 0, stream>>>(accD, proj_w, x, (float*)d_out);
}